// Round 12
// baseline (215.274 us; speedup 1.0000x reference)
//
#include <hip/hip_runtime.h>
#include <hip/hip_bf16.h>

#define N_NODES 50000
#define N_EDGES 800000
#define HEADS   4
#define NEG_SLOPE 0.2f
#define SB      256
#define NB      ((N_NODES + SB - 1) / SB)   // 196 blocks for cnt-zeroing
#define NTILE   17                    // 16 xt tiles + 1 attention tile
#define CAP     64                    // bucket capacity; P(deg>64)~1e-18/node
#define NT      ((N_NODES + 63) / 64)       // 782 transform blocks
#define NS      ((N_EDGES + 255) / 256)     // 3125 scatter blocks

typedef __attribute__((ext_vector_type(8))) _Float16 half8;  // 8 f16 (4 VGPRs)
typedef __attribute__((ext_vector_type(4))) float f32x4;     // MFMA acc

template <typename T> __device__ __forceinline__ float cvt(T v);
template <> __device__ __forceinline__ float cvt<float>(float v) { return v; }
template <> __device__ __forceinline__ float cvt<__hip_bfloat16>(__hip_bfloat16 v) {
    return __bfloat162float(v);
}
__device__ __forceinline__ unsigned short f2h(float f) {     // f32 -> f16 bits (RNE)
    _Float16 h = (_Float16)f;
    return __builtin_bit_cast(unsigned short, h);
}
__device__ __forceinline__ float hbits(unsigned short u) {   // f16 bits -> f32
    return (float)__builtin_bit_cast(_Float16, u);           // folds into v_fma_mix
}
__device__ __forceinline__ int probe_fp32(const unsigned* xw) {
    int sane = 0;
    for (int j = 0; j < 64; ++j) {
        unsigned e = (xw[j] >> 7) & 0xFF;    // exponent of low half viewed as bf16
        sane += (e >= 90 && e <= 141);
    }
    return sane < 32;                        // junk low halves => fp32 buffer
}

// ---------------- prep: fold att vectors + pack 17 B-fragment tiles (f16) ----
// Tiles 0..15: column-permuted W so xt layout is [node][ch*4+h]; tile 16:
// cols 0..3 = WaS (a_src), 4..7 = WaD (a_dst), 8..15 = 0. B layout (HW-
// verified R9-R11): value(l, q, j) = B[k = q*32 + (l>>4)*8 + j][n = l&15].
template <typename T>
__device__ __forceinline__ void prep_body(const T* __restrict__ W,
                                          const T* __restrict__ att_src,
                                          const T* __restrict__ att_dst,
                                          unsigned short* __restrict__ Bpack) {
    __shared__ float waS[256], waD[256];     // [k*4+h]
    int t = threadIdx.x;                     // t = k*4 + h
    int k = t >> 2, h = t & 3;
    float s = 0.f, d = 0.f;
    for (int c = 0; c < 64; ++c) {
        float w = cvt<T>(W[k * 256 + h * 64 + c]);
        s = fmaf(w, cvt<T>(att_src[h * 64 + c]), s);
        d = fmaf(w, cvt<T>(att_dst[h * 64 + c]), d);
    }
    waS[t] = s;
    waD[t] = d;
    __syncthreads();
    for (int idx = threadIdx.x; idx < NTILE * 128; idx += 256) {
        int tt = idx >> 7, q = (idx >> 6) & 1, l = idx & 63;
        int n = l & 15;
        int kbase = q * 32 + ((l >> 4) & 3) * 8;
        if (tt < 16) {
            int oc = ((tt * 16 + n) & 3) * 64 + ((tt * 16 + n) >> 2);
#pragma unroll
            for (int j = 0; j < 8; ++j)
                Bpack[idx * 8 + j] = f2h(cvt<T>(W[(kbase + j) * 256 + oc]));
        } else {
#pragma unroll
            for (int j = 0; j < 8; ++j) {
                int kk = kbase + j;
                float v = (n < 4) ? waS[kk * 4 + n]
                        : (n < 8) ? waD[kk * 4 + (n - 4)] : 0.f;
                Bpack[idx * 8 + j] = f2h(v);
            }
        }
    }
}

// ------------- fused: zero cnt + dtype probes (block 0) + prep (block NB) ----
// flags[0]: edge_index is int64. flags[1]: float inputs are fp32.
__global__ __launch_bounds__(256) void k_init(const unsigned* __restrict__ xw,
                                              const int* __restrict__ ei,
                                              const void* __restrict__ W,
                                              const void* __restrict__ att_src,
                                              const void* __restrict__ att_dst,
                                              int* __restrict__ cnt,
                                              int* __restrict__ flags,
                                              unsigned short* __restrict__ Bpack) {
    if (blockIdx.x < NB) {
        int i = blockIdx.x * blockDim.x + threadIdx.x;
        if (i < N_NODES) cnt[i] = 0;
        if (blockIdx.x == 0 && threadIdx.x == 0) {
            int all0 = 1;
            for (int j = 1; j < 64; j += 2) all0 &= (ei[j] == 0);
            flags[0] = all0;
            flags[1] = probe_fp32(xw);
        }
    } else {
        __shared__ int f32sh;
        if (threadIdx.x == 0) f32sh = probe_fp32(xw);   // local probe (race-free)
        __syncthreads();
        if (f32sh)
            prep_body<float>((const float*)W, (const float*)att_src,
                             (const float*)att_dst, Bpack);
        else
            prep_body<__hip_bfloat16>((const __hip_bfloat16*)W,
                                      (const __hip_bfloat16*)att_src,
                                      (const __hip_bfloat16*)att_dst, Bpack);
    }
}

// ---------------- MFMA transform body: xt = x @ Wp + attention logits --------
// Block = 64 rows, 4 waves; wave w: rows 16w..16w+15, 17 n-tiles, K=64.
// C layout (HW-verified): col=lane&15, row=quad*4+reg. Tile 16 cols 0..7 are
// a_src/a_dst heads -> direct fp32 global writes. xt stored as f16.
template <typename T>
__device__ __forceinline__ void gemm_body(const T* __restrict__ x,
                                          const unsigned short* __restrict__ Bpack,
                                          unsigned short* __restrict__ xt,
                                          float* __restrict__ a_src,
                                          float* __restrict__ a_dst) {
    __shared__ unsigned short tile[64 * 264];   // row pitch 528 B (16B-aligned)
    const int tid = threadIdx.x;
    const int wav = tid >> 6, lane = tid & 63;
    const int quad = lane >> 4, r15 = lane & 15;
    const int m0 = blockIdx.x * 64;
    int gr = m0 + wav * 16 + r15;               // this lane's A row (m = lane&15)
    if (gr >= N_NODES) gr = N_NODES - 1;        // clamp; stores guarded
    half8 afrag[2];
#pragma unroll
    for (int q = 0; q < 2; ++q) {
        const T* xp = x + (size_t)gr * 64 + q * 32 + quad * 8;
#pragma unroll
        for (int j = 0; j < 8; ++j)
            afrag[q][j] = (_Float16)cvt<T>(xp[j]);
    }
    f32x4 acc[NTILE];
#pragma unroll
    for (int t = 0; t < NTILE; ++t) acc[t] = (f32x4){0.f, 0.f, 0.f, 0.f};
    const half8* bp = (const half8*)Bpack;
#pragma unroll
    for (int t = 0; t < NTILE; ++t) {
        half8 b0 = bp[(t * 2 + 0) * 64 + lane];   // L1-resident (34 KB total)
        half8 b1 = bp[(t * 2 + 1) * 64 + lane];
        acc[t] = __builtin_amdgcn_mfma_f32_16x16x32_f16(afrag[0], b0, acc[t], 0, 0, 0);
        acc[t] = __builtin_amdgcn_mfma_f32_16x16x32_f16(afrag[1], b1, acc[t], 0, 0, 0);
    }
#pragma unroll
    for (int t = 0; t < 16; ++t)
#pragma unroll
        for (int r = 0; r < 4; ++r)
            tile[(wav * 16 + quad * 4 + r) * 264 + t * 16 + r15] = f2h(acc[t][r]);
    if (r15 < 8) {                               // tile 16: attention logits, fp32
#pragma unroll
        for (int r = 0; r < 4; ++r) {
            int grow = m0 + wav * 16 + quad * 4 + r;
            if (grow < N_NODES) {
                if (r15 < 4) a_src[grow * HEADS + r15]       = acc[16][r];
                else         a_dst[grow * HEADS + (r15 - 4)] = acc[16][r];
            }
        }
    }
    __syncthreads();
    for (int idx = tid; idx < 64 * 32; idx += 256) {   // 64 rows x 32 chunks x 16B
        int row = idx >> 5, cc = idx & 31;
        int grow = m0 + row;
        if (grow < N_NODES) {
            uint4 v = *(const uint4*)&tile[row * 264 + cc * 8];
            *(uint4*)(xt + (size_t)grow * 256 + cc * 8) = v;
        }
    }
}

// ---------------- fused mid: transform (blocks 0..NT-1) ∥ scatter (rest) -----
// The two halves touch disjoint data (x->xt vs ei->col_pad), so they execute
// concurrently across CUs instead of serializing as two launches.
__global__ __launch_bounds__(256) void k_mid(const void* __restrict__ x,
                                             const unsigned short* __restrict__ Bpack,
                                             const int* __restrict__ ei,
                                             const int* __restrict__ flags,
                                             int* __restrict__ cnt,
                                             int* __restrict__ col_pad,
                                             unsigned short* __restrict__ xt,
                                             float* __restrict__ a_src,
                                             float* __restrict__ a_dst) {
    if (blockIdx.x < NT) {
        if (flags[1]) gemm_body<float>((const float*)x, Bpack, xt, a_src, a_dst);
        else          gemm_body<__hip_bfloat16>((const __hip_bfloat16*)x, Bpack, xt,
                                                a_src, a_dst);
    } else {
        int t = (blockIdx.x - NT) * 256 + threadIdx.x;
        if (t >= N_EDGES) return;
        int src, dst;
        if (flags[0]) { src = ei[2 * t]; dst = ei[2 * N_EDGES + 2 * t]; }  // int64
        else          { src = ei[t];     dst = ei[N_EDGES + t]; }          // int32
        int pos = atomicAdd(cnt + dst, 1);
        if (pos < CAP) col_pad[dst * CAP + pos] = src;   // P(overflow) ~ 1e-18/node
    }
}

// ---------------- fused aggregate: softmax + weighted sum + mean/bias/relu/fc
// One wave per dst node; lane = channel. Buckets: n = cnt[wid], cols at
// col_pad[wid*CAP + ...]. Self-loop analytic. Chunk of 64 edges: lane i stages
// (col, pe) in a wave-private LDS slice; j-loop x8 keeps 8 independent 512 B
// xt gathers in flight; f16 xt consumed via v_fma_mix (cvt folded into FMA).
template <typename T>
__device__ __forceinline__ void agg_body(const int* __restrict__ cnt,
                                         const int* __restrict__ col_pad,
                                         const float* __restrict__ a_src,
                                         const float* __restrict__ a_dst,
                                         const unsigned short* __restrict__ xt,
                                         const T* __restrict__ bias,
                                         const T* __restrict__ fc_w,
                                         const T* __restrict__ fc_b,
                                         float* __restrict__ out) {
    __shared__ int    cS[4][64];
    __shared__ float4 peS[4][64];
    const int tid = threadIdx.x;
    const int wav = tid >> 6, lane = tid & 63;
    const int wid = (blockIdx.x * blockDim.x + tid) >> 6;   // dst node
    if (wid >= N_NODES) return;
    int n = cnt[wid]; n = n > CAP ? CAP : n;
    const float4 ad = ((const float4*)a_dst)[wid];          // uniform
    const float4 as_self = ((const float4*)a_src)[wid];
    float v0 = 0.f, v1 = 0.f, v2 = 0.f, v3 = 0.f;
    float sp0 = 0.f, sp1 = 0.f, sp2 = 0.f, sp3 = 0.f;       // lane-parallel denom
    for (int base = 0; base < n; base += 64) {
        int m = n - base; m = m > 64 ? 64 : m;
        if (lane < m) {
            int mycol = col_pad[wid * CAP + base + lane];   // coalesced
            const float4 as = ((const float4*)a_src)[mycol];
            float e0 = as.x + ad.x, e1 = as.y + ad.y;
            float e2 = as.z + ad.z, e3 = as.w + ad.w;
            e0 = e0 > 0.f ? e0 : NEG_SLOPE * e0;  e1 = e1 > 0.f ? e1 : NEG_SLOPE * e1;
            e2 = e2 > 0.f ? e2 : NEG_SLOPE * e2;  e3 = e3 > 0.f ? e3 : NEG_SLOPE * e3;
            float4 pe = make_float4(__expf(e0), __expf(e1), __expf(e2), __expf(e3));
            cS[wav][lane] = mycol;
            peS[wav][lane] = pe;
            sp0 += pe.x; sp1 += pe.y; sp2 += pe.z; sp3 += pe.w;
        }
        int j = 0;
        for (; j + 8 <= m; j += 8) {
            int s0 = cS[wav][j],     s1 = cS[wav][j + 1];
            int s2 = cS[wav][j + 2], s3 = cS[wav][j + 3];
            int s4 = cS[wav][j + 4], s5 = cS[wav][j + 5];
            int s6 = cS[wav][j + 6], s7 = cS[wav][j + 7];
            const ushort4 xA = *(const ushort4*)(xt + (size_t)s0 * 256 + lane * 4);
            const ushort4 xB = *(const ushort4*)(xt + (size_t)s1 * 256 + lane * 4);
            const ushort4 xC = *(const ushort4*)(xt + (size_t)s2 * 256 + lane * 4);
            const ushort4 xD = *(const ushort4*)(xt + (size_t)s3 * 256 + lane * 4);
            const ushort4 xE = *(const ushort4*)(xt + (size_t)s4 * 256 + lane * 4);
            const ushort4 xF = *(const ushort4*)(xt + (size_t)s5 * 256 + lane * 4);
            const ushort4 xG = *(const ushort4*)(xt + (size_t)s6 * 256 + lane * 4);
            const ushort4 xH = *(const ushort4*)(xt + (size_t)s7 * 256 + lane * 4);
            float4 p0 = peS[wav][j],     p1 = peS[wav][j + 1];
            float4 p2 = peS[wav][j + 2], p3 = peS[wav][j + 3];
            float4 p4 = peS[wav][j + 4], p5 = peS[wav][j + 5];
            float4 p6 = peS[wav][j + 6], p7 = peS[wav][j + 7];
            v0 = fmaf(p0.x, hbits(xA.x), v0); v1 = fmaf(p0.y, hbits(xA.y), v1);
            v2 = fmaf(p0.z, hbits(xA.z), v2); v3 = fmaf(p0.w, hbits(xA.w), v3);
            v0 = fmaf(p1.x, hbits(xB.x), v0); v1 = fmaf(p1.y, hbits(xB.y), v1);
            v2 = fmaf(p1.z, hbits(xB.z), v2); v3 = fmaf(p1.w, hbits(xB.w), v3);
            v0 = fmaf(p2.x, hbits(xC.x), v0); v1 = fmaf(p2.y, hbits(xC.y), v1);
            v2 = fmaf(p2.z, hbits(xC.z), v2); v3 = fmaf(p2.w, hbits(xC.w), v3);
            v0 = fmaf(p3.x, hbits(xD.x), v0); v1 = fmaf(p3.y, hbits(xD.y), v1);
            v2 = fmaf(p3.z, hbits(xD.z), v2); v3 = fmaf(p3.w, hbits(xD.w), v3);
            v0 = fmaf(p4.x, hbits(xE.x), v0); v1 = fmaf(p4.y, hbits(xE.y), v1);
            v2 = fmaf(p4.z, hbits(xE.z), v2); v3 = fmaf(p4.w, hbits(xE.w), v3);
            v0 = fmaf(p5.x, hbits(xF.x), v0); v1 = fmaf(p5.y, hbits(xF.y), v1);
            v2 = fmaf(p5.z, hbits(xF.z), v2); v3 = fmaf(p5.w, hbits(xF.w), v3);
            v0 = fmaf(p6.x, hbits(xG.x), v0); v1 = fmaf(p6.y, hbits(xG.y), v1);
            v2 = fmaf(p6.z, hbits(xG.z), v2); v3 = fmaf(p6.w, hbits(xG.w), v3);
            v0 = fmaf(p7.x, hbits(xH.x), v0); v1 = fmaf(p7.y, hbits(xH.y), v1);
            v2 = fmaf(p7.z, hbits(xH.z), v2); v3 = fmaf(p7.w, hbits(xH.w), v3);
        }
        for (; j < m; ++j) {
            int s0 = cS[wav][j];
            const ushort4 xA = *(const ushort4*)(xt + (size_t)s0 * 256 + lane * 4);
            float4 p0 = peS[wav][j];
            v0 = fmaf(p0.x, hbits(xA.x), v0); v1 = fmaf(p0.y, hbits(xA.y), v1);
            v2 = fmaf(p0.z, hbits(xA.z), v2); v3 = fmaf(p0.w, hbits(xA.w), v3);
        }
    }
#pragma unroll
    for (int msk = 1; msk < 64; msk <<= 1) {
        sp0 += __shfl_xor(sp0, msk, 64); sp1 += __shfl_xor(sp1, msk, 64);
        sp2 += __shfl_xor(sp2, msk, 64); sp3 += __shfl_xor(sp3, msk, 64);
    }
    {   // self loop: e = a_src[wid] + a_dst[wid], uniform across lanes
        float e0 = as_self.x + ad.x, e1 = as_self.y + ad.y;
        float e2 = as_self.z + ad.z, e3 = as_self.w + ad.w;
        e0 = e0 > 0.f ? e0 : NEG_SLOPE * e0;  e1 = e1 > 0.f ? e1 : NEG_SLOPE * e1;
        e2 = e2 > 0.f ? e2 : NEG_SLOPE * e2;  e3 = e3 > 0.f ? e3 : NEG_SLOPE * e3;
        float q0 = __expf(e0), q1 = __expf(e1), q2 = __expf(e2), q3 = __expf(e3);
        sp0 += q0; sp1 += q1; sp2 += q2; sp3 += q3;
        const ushort4 xS = *(const ushort4*)(xt + (size_t)wid * 256 + lane * 4);
        v0 = fmaf(q0, hbits(xS.x), v0); v1 = fmaf(q1, hbits(xS.y), v1);
        v2 = fmaf(q2, hbits(xS.z), v2); v3 = fmaf(q3, hbits(xS.w), v3);
    }
    float o = (v0 / sp0 + v1 / sp1 + v2 / sp2 + v3 / sp3) * 0.25f + cvt<T>(bias[lane]);
    o = o > 0.f ? o : 0.f;                      // relu
    o *= cvt<T>(fc_w[lane]);                    // fc_w is [64,1]
#pragma unroll
    for (int off = 32; off > 0; off >>= 1) o += __shfl_down(o, off, 64);
    if (lane == 0) out[wid] = o + cvt<T>(fc_b[0]);   // fp32 output
}

__global__ __launch_bounds__(256) void k_aggregate(const int* __restrict__ cnt,
                                                   const int* __restrict__ col_pad,
                                                   const float* __restrict__ a_src,
                                                   const float* __restrict__ a_dst,
                                                   const unsigned short* __restrict__ xt,
                                                   const void* __restrict__ bias,
                                                   const void* __restrict__ fc_w,
                                                   const void* __restrict__ fc_b,
                                                   const int* __restrict__ flags,
                                                   float* __restrict__ out) {
    if (flags[1])
        agg_body<float>(cnt, col_pad, a_src, a_dst, xt, (const float*)bias,
                        (const float*)fc_w, (const float*)fc_b, out);
    else
        agg_body<__hip_bfloat16>(cnt, col_pad, a_src, a_dst, xt,
                                 (const __hip_bfloat16*)bias,
                                 (const __hip_bfloat16*)fc_w,
                                 (const __hip_bfloat16*)fc_b, out);
}

extern "C" void kernel_launch(void* const* d_in, const int* in_sizes, int n_in,
                              void* d_out, int out_size, void* d_ws, size_t ws_size,
                              hipStream_t stream) {
    const void* x       = d_in[0];
    const int*  ei      = (const int*)d_in[1];
    const void* W       = d_in[2];
    const void* att_src = d_in[3];
    const void* att_dst = d_in[4];
    const void* bias    = d_in[5];
    const void* fc_w    = d_in[6];
    const void* fc_b    = d_in[7];
    float* out = (float*)d_out;

    char* wsb = (char*)d_ws;
    unsigned short* xt = (unsigned short*)wsb;                   // 25.6 MB (f16)
    unsigned short* Bpack = (unsigned short*)(wsb + (size_t)N_NODES * 512); // 34 KB
    float*  a_src  = (float*)(Bpack + NTILE * 1024);             // 800 KB (16B aligned)
    float*  a_dst  = a_src + N_NODES * HEADS;                    // 800 KB (16B aligned)
    int*    col_pad= (int*)(a_dst + N_NODES * HEADS);            // 12.8 MB
    int*    cnt    = col_pad + (size_t)N_NODES * CAP;            // 200 KB
    int*    flags  = cnt + N_NODES;

    k_init<<<NB + 1, 256, 0, stream>>>((const unsigned*)x, ei, W, att_src, att_dst,
                                       cnt, flags, Bpack);
    k_mid<<<NT + NS, 256, 0, stream>>>(x, Bpack, ei, flags, cnt, col_pad,
                                       xt, a_src, a_dst);
    k_aggregate<<<((size_t)N_NODES * 64 + 255) / 256, 256, 0, stream>>>(
        cnt, col_pad, a_src, a_dst, xt, bias, fc_w, fc_b, flags, out);
}

// Round 13
// 214.654 us; speedup vs baseline: 1.0029x; 1.0029x over previous
//
#include <hip/hip_runtime.h>
#include <hip/hip_bf16.h>

#define N_NODES 50000
#define N_EDGES 800000
#define HEADS   4
#define NEG_SLOPE 0.2f
#define SB      256
#define NB      ((N_NODES + SB - 1) / SB)   // 196 blocks for cnt-zeroing
#define NTILE   17                    // 16 xt tiles + 1 attention tile
#define CAP     64                    // bucket capacity; P(deg>64)~1e-18/node

typedef __attribute__((ext_vector_type(8))) _Float16 half8;  // 8 f16 (4 VGPRs)
typedef __attribute__((ext_vector_type(4))) float f32x4;     // MFMA acc

template <typename T> __device__ __forceinline__ float cvt(T v);
template <> __device__ __forceinline__ float cvt<float>(float v) { return v; }
template <> __device__ __forceinline__ float cvt<__hip_bfloat16>(__hip_bfloat16 v) {
    return __bfloat162float(v);
}
__device__ __forceinline__ unsigned short f2h(float f) {     // f32 -> f16 bits (RNE)
    _Float16 h = (_Float16)f;
    return __builtin_bit_cast(unsigned short, h);
}
__device__ __forceinline__ float hbits(unsigned short u) {   // f16 bits -> f32
    return (float)__builtin_bit_cast(_Float16, u);           // folds into v_fma_mix
}
__device__ __forceinline__ int probe_fp32(const unsigned* xw) {
    int sane = 0;
    for (int j = 0; j < 64; ++j) {
        unsigned e = (xw[j] >> 7) & 0xFF;    // exponent of low half viewed as bf16
        sane += (e >= 90 && e <= 141);
    }
    return sane < 32;                        // junk low halves => fp32 buffer
}

// ---------------- prep: fold att vectors + pack 17 B-fragment tiles (f16) ----
// Tiles 0..15: column-permuted W so xt layout is [node][ch*4+h]; tile 16:
// cols 0..3 = WaS (a_src), 4..7 = WaD (a_dst), 8..15 = 0. B layout (HW-
// verified R9-R12): value(l, q, j) = B[k = q*32 + (l>>4)*8 + j][n = l&15].
template <typename T>
__device__ __forceinline__ void prep_body(const T* __restrict__ W,
                                          const T* __restrict__ att_src,
                                          const T* __restrict__ att_dst,
                                          unsigned short* __restrict__ Bpack,
                                          float* __restrict__ waS,
                                          float* __restrict__ waD) {
    int t = threadIdx.x;                     // t = k*4 + h
    int k = t >> 2, h = t & 3;
    float s = 0.f, d = 0.f;
    for (int c = 0; c < 64; ++c) {
        float w = cvt<T>(W[k * 256 + h * 64 + c]);
        s = fmaf(w, cvt<T>(att_src[h * 64 + c]), s);
        d = fmaf(w, cvt<T>(att_dst[h * 64 + c]), d);
    }
    waS[t] = s;
    waD[t] = d;
    __syncthreads();
    for (int idx = threadIdx.x; idx < NTILE * 128; idx += 256) {
        int tt = idx >> 7, q = (idx >> 6) & 1, l = idx & 63;
        int n = l & 15;
        int kbase = q * 32 + ((l >> 4) & 3) * 8;
        if (tt < 16) {
            int oc = ((tt * 16 + n) & 3) * 64 + ((tt * 16 + n) >> 2);
#pragma unroll
            for (int j = 0; j < 8; ++j)
                Bpack[idx * 8 + j] = f2h(cvt<T>(W[(kbase + j) * 256 + oc]));
        } else {
#pragma unroll
            for (int j = 0; j < 8; ++j) {
                int kk = kbase + j;
                float v = (n < 4) ? waS[kk * 4 + n]
                        : (n < 8) ? waD[kk * 4 + (n - 4)] : 0.f;
                Bpack[idx * 8 + j] = f2h(v);
            }
        }
    }
}

// ------------- fused: zero cnt + dtype probes (block 0) + prep (block NB) ----
// flags[0]: edge_index is int64. flags[1]: float inputs are fp32.
__global__ __launch_bounds__(256) void k_init(const unsigned* __restrict__ xw,
                                              const int* __restrict__ ei,
                                              const void* __restrict__ W,
                                              const void* __restrict__ att_src,
                                              const void* __restrict__ att_dst,
                                              int* __restrict__ cnt,
                                              int* __restrict__ flags,
                                              unsigned short* __restrict__ Bpack) {
    __shared__ float waS[256], waD[256];     // hoisted: single allocation
    if (blockIdx.x < NB) {
        int i = blockIdx.x * blockDim.x + threadIdx.x;
        if (i < N_NODES) cnt[i] = 0;
        if (blockIdx.x == 0 && threadIdx.x == 0) {
            int all0 = 1;
            for (int j = 1; j < 64; j += 2) all0 &= (ei[j] == 0);
            flags[0] = all0;
            flags[1] = probe_fp32(xw);
        }
    } else {
        __shared__ int f32sh;
        if (threadIdx.x == 0) f32sh = probe_fp32(xw);   // local probe (race-free)
        __syncthreads();
        if (f32sh)
            prep_body<float>((const float*)W, (const float*)att_src,
                             (const float*)att_dst, Bpack, waS, waD);
        else
            prep_body<__hip_bfloat16>((const __hip_bfloat16*)W,
                                      (const __hip_bfloat16*)att_src,
                                      (const __hip_bfloat16*)att_dst, Bpack,
                                      waS, waD);
    }
}

// ---------------- single-pass bucket scatter (no LDS, full occupancy) --------
__global__ __launch_bounds__(256) void k_scatter(const int* __restrict__ ei,
                                                 const int* __restrict__ flags,
                                                 int* __restrict__ cnt,
                                                 int* __restrict__ col_pad) {
    int t = blockIdx.x * blockDim.x + threadIdx.x;
    if (t >= N_EDGES) return;
    int src, dst;
    if (flags[0]) { src = ei[2 * t]; dst = ei[2 * N_EDGES + 2 * t]; }  // int64 low words
    else          { src = ei[t];     dst = ei[N_EDGES + t]; }          // int32 layout
    int pos = atomicAdd(cnt + dst, 1);
    if (pos < CAP) col_pad[dst * CAP + pos] = src;   // P(overflow) ~ 1e-18/node
}

// ---------------- MFMA transform body: xt = x @ Wp + attention logits --------
// Block = 64 rows, 4 waves; wave w: rows 16w..16w+15, 17 n-tiles, K=64.
// C layout (HW-verified): col=lane&15, row=quad*4+reg. Tile 16 cols 0..7 are
// a_src/a_dst heads -> direct fp32 global writes. xt stored as f16.
// tile passed in from kernel scope (avoids duplicate LDS per instantiation).
template <typename T>
__device__ __forceinline__ void gemm_body(const T* __restrict__ x,
                                          const unsigned short* __restrict__ Bpack,
                                          unsigned short* __restrict__ xt,
                                          float* __restrict__ a_src,
                                          float* __restrict__ a_dst,
                                          unsigned short* __restrict__ tile) {
    const int tid = threadIdx.x;
    const int wav = tid >> 6, lane = tid & 63;
    const int quad = lane >> 4, r15 = lane & 15;
    const int m0 = blockIdx.x * 64;
    int gr = m0 + wav * 16 + r15;               // this lane's A row (m = lane&15)
    if (gr >= N_NODES) gr = N_NODES - 1;        // clamp; stores guarded
    half8 afrag[2];
#pragma unroll
    for (int q = 0; q < 2; ++q) {
        const T* xp = x + (size_t)gr * 64 + q * 32 + quad * 8;
#pragma unroll
        for (int j = 0; j < 8; ++j)
            afrag[q][j] = (_Float16)cvt<T>(xp[j]);
    }
    f32x4 acc[NTILE];
#pragma unroll
    for (int t = 0; t < NTILE; ++t) acc[t] = (f32x4){0.f, 0.f, 0.f, 0.f};
    const half8* bp = (const half8*)Bpack;
#pragma unroll
    for (int t = 0; t < NTILE; ++t) {
        half8 b0 = bp[(t * 2 + 0) * 64 + lane];   // L1-resident (34 KB total)
        half8 b1 = bp[(t * 2 + 1) * 64 + lane];
        acc[t] = __builtin_amdgcn_mfma_f32_16x16x32_f16(afrag[0], b0, acc[t], 0, 0, 0);
        acc[t] = __builtin_amdgcn_mfma_f32_16x16x32_f16(afrag[1], b1, acc[t], 0, 0, 0);
    }
#pragma unroll
    for (int t = 0; t < 16; ++t)
#pragma unroll
        for (int r = 0; r < 4; ++r)
            tile[(wav * 16 + quad * 4 + r) * 264 + t * 16 + r15] = f2h(acc[t][r]);
    if (r15 < 8) {                               // tile 16: attention logits, fp32
#pragma unroll
        for (int r = 0; r < 4; ++r) {
            int grow = m0 + wav * 16 + quad * 4 + r;
            if (grow < N_NODES) {
                if (r15 < 4) a_src[grow * HEADS + r15]       = acc[16][r];
                else         a_dst[grow * HEADS + (r15 - 4)] = acc[16][r];
            }
        }
    }
    __syncthreads();
    for (int idx = tid; idx < 64 * 32; idx += 256) {   // 64 rows x 32 chunks x 16B
        int row = idx >> 5, cc = idx & 31;
        int grow = m0 + row;
        if (grow < N_NODES) {
            uint4 v = *(const uint4*)&tile[row * 264 + cc * 8];
            *(uint4*)(xt + (size_t)grow * 256 + cc * 8) = v;
        }
    }
}

__global__ __launch_bounds__(256) void k_transform(const void* __restrict__ x,
                                                   const unsigned short* __restrict__ Bpack,
                                                   const int* __restrict__ flags,
                                                   unsigned short* __restrict__ xt,
                                                   float* __restrict__ a_src,
                                                   float* __restrict__ a_dst) {
    __shared__ unsigned short tile[64 * 264];   // hoisted: ONE 33.8 KB allocation
    if (flags[1]) gemm_body<float>((const float*)x, Bpack, xt, a_src, a_dst, tile);
    else          gemm_body<__hip_bfloat16>((const __hip_bfloat16*)x, Bpack, xt,
                                            a_src, a_dst, tile);
}

// ---------------- fused aggregate: softmax + weighted sum + mean/bias/relu/fc
// One wave per dst node; lane = channel. Buckets: n = cnt[wid], cols at
// col_pad[wid*CAP + ...]. Self-loop analytic. Chunk of 64 edges: lane i stages
// (col, pe) in a wave-private LDS slice; j-loop x8 keeps 8 independent 512 B
// xt gathers in flight; f16 xt consumed via v_fma_mix (cvt folded into FMA).
template <typename T>
__device__ __forceinline__ void agg_body(const int* __restrict__ cnt,
                                         const int* __restrict__ col_pad,
                                         const float* __restrict__ a_src,
                                         const float* __restrict__ a_dst,
                                         const unsigned short* __restrict__ xt,
                                         const T* __restrict__ bias,
                                         const T* __restrict__ fc_w,
                                         const T* __restrict__ fc_b,
                                         float* __restrict__ out,
                                         int* __restrict__ cS,
                                         float4* __restrict__ peS) {
    const int tid = threadIdx.x;
    const int wav = tid >> 6, lane = tid & 63;
    const int wid = (blockIdx.x * blockDim.x + tid) >> 6;   // dst node
    if (wid >= N_NODES) return;
    int* cSw = cS + wav * 64;
    float4* peSw = peS + wav * 64;
    int n = cnt[wid]; n = n > CAP ? CAP : n;
    const float4 ad = ((const float4*)a_dst)[wid];          // uniform
    const float4 as_self = ((const float4*)a_src)[wid];
    float v0 = 0.f, v1 = 0.f, v2 = 0.f, v3 = 0.f;
    float sp0 = 0.f, sp1 = 0.f, sp2 = 0.f, sp3 = 0.f;       // lane-parallel denom
    for (int base = 0; base < n; base += 64) {
        int m = n - base; m = m > 64 ? 64 : m;
        if (lane < m) {
            int mycol = col_pad[wid * CAP + base + lane];   // coalesced
            const float4 as = ((const float4*)a_src)[mycol];
            float e0 = as.x + ad.x, e1 = as.y + ad.y;
            float e2 = as.z + ad.z, e3 = as.w + ad.w;
            e0 = e0 > 0.f ? e0 : NEG_SLOPE * e0;  e1 = e1 > 0.f ? e1 : NEG_SLOPE * e1;
            e2 = e2 > 0.f ? e2 : NEG_SLOPE * e2;  e3 = e3 > 0.f ? e3 : NEG_SLOPE * e3;
            float4 pe = make_float4(__expf(e0), __expf(e1), __expf(e2), __expf(e3));
            cSw[lane] = mycol;
            peSw[lane] = pe;
            sp0 += pe.x; sp1 += pe.y; sp2 += pe.z; sp3 += pe.w;
        }
        int j = 0;
        for (; j + 8 <= m; j += 8) {
            int s0 = cSw[j],     s1 = cSw[j + 1];
            int s2 = cSw[j + 2], s3 = cSw[j + 3];
            int s4 = cSw[j + 4], s5 = cSw[j + 5];
            int s6 = cSw[j + 6], s7 = cSw[j + 7];
            const ushort4 xA = *(const ushort4*)(xt + (size_t)s0 * 256 + lane * 4);
            const ushort4 xB = *(const ushort4*)(xt + (size_t)s1 * 256 + lane * 4);
            const ushort4 xC = *(const ushort4*)(xt + (size_t)s2 * 256 + lane * 4);
            const ushort4 xD = *(const ushort4*)(xt + (size_t)s3 * 256 + lane * 4);
            const ushort4 xE = *(const ushort4*)(xt + (size_t)s4 * 256 + lane * 4);
            const ushort4 xF = *(const ushort4*)(xt + (size_t)s5 * 256 + lane * 4);
            const ushort4 xG = *(const ushort4*)(xt + (size_t)s6 * 256 + lane * 4);
            const ushort4 xH = *(const ushort4*)(xt + (size_t)s7 * 256 + lane * 4);
            float4 p0 = peSw[j],     p1 = peSw[j + 1];
            float4 p2 = peSw[j + 2], p3 = peSw[j + 3];
            float4 p4 = peSw[j + 4], p5 = peSw[j + 5];
            float4 p6 = peSw[j + 6], p7 = peSw[j + 7];
            v0 = fmaf(p0.x, hbits(xA.x), v0); v1 = fmaf(p0.y, hbits(xA.y), v1);
            v2 = fmaf(p0.z, hbits(xA.z), v2); v3 = fmaf(p0.w, hbits(xA.w), v3);
            v0 = fmaf(p1.x, hbits(xB.x), v0); v1 = fmaf(p1.y, hbits(xB.y), v1);
            v2 = fmaf(p1.z, hbits(xB.z), v2); v3 = fmaf(p1.w, hbits(xB.w), v3);
            v0 = fmaf(p2.x, hbits(xC.x), v0); v1 = fmaf(p2.y, hbits(xC.y), v1);
            v2 = fmaf(p2.z, hbits(xC.z), v2); v3 = fmaf(p2.w, hbits(xC.w), v3);
            v0 = fmaf(p3.x, hbits(xD.x), v0); v1 = fmaf(p3.y, hbits(xD.y), v1);
            v2 = fmaf(p3.z, hbits(xD.z), v2); v3 = fmaf(p3.w, hbits(xD.w), v3);
            v0 = fmaf(p4.x, hbits(xE.x), v0); v1 = fmaf(p4.y, hbits(xE.y), v1);
            v2 = fmaf(p4.z, hbits(xE.z), v2); v3 = fmaf(p4.w, hbits(xE.w), v3);
            v0 = fmaf(p5.x, hbits(xF.x), v0); v1 = fmaf(p5.y, hbits(xF.y), v1);
            v2 = fmaf(p5.z, hbits(xF.z), v2); v3 = fmaf(p5.w, hbits(xF.w), v3);
            v0 = fmaf(p6.x, hbits(xG.x), v0); v1 = fmaf(p6.y, hbits(xG.y), v1);
            v2 = fmaf(p6.z, hbits(xG.z), v2); v3 = fmaf(p6.w, hbits(xG.w), v3);
            v0 = fmaf(p7.x, hbits(xH.x), v0); v1 = fmaf(p7.y, hbits(xH.y), v1);
            v2 = fmaf(p7.z, hbits(xH.z), v2); v3 = fmaf(p7.w, hbits(xH.w), v3);
        }
        for (; j < m; ++j) {
            int s0 = cSw[j];
            const ushort4 xA = *(const ushort4*)(xt + (size_t)s0 * 256 + lane * 4);
            float4 p0 = peSw[j];
            v0 = fmaf(p0.x, hbits(xA.x), v0); v1 = fmaf(p0.y, hbits(xA.y), v1);
            v2 = fmaf(p0.z, hbits(xA.z), v2); v3 = fmaf(p0.w, hbits(xA.w), v3);
        }
    }
#pragma unroll
    for (int msk = 1; msk < 64; msk <<= 1) {
        sp0 += __shfl_xor(sp0, msk, 64); sp1 += __shfl_xor(sp1, msk, 64);
        sp2 += __shfl_xor(sp2, msk, 64); sp3 += __shfl_xor(sp3, msk, 64);
    }
    {   // self loop: e = a_src[wid] + a_dst[wid], uniform across lanes
        float e0 = as_self.x + ad.x, e1 = as_self.y + ad.y;
        float e2 = as_self.z + ad.z, e3 = as_self.w + ad.w;
        e0 = e0 > 0.f ? e0 : NEG_SLOPE * e0;  e1 = e1 > 0.f ? e1 : NEG_SLOPE * e1;
        e2 = e2 > 0.f ? e2 : NEG_SLOPE * e2;  e3 = e3 > 0.f ? e3 : NEG_SLOPE * e3;
        float q0 = __expf(e0), q1 = __expf(e1), q2 = __expf(e2), q3 = __expf(e3);
        sp0 += q0; sp1 += q1; sp2 += q2; sp3 += q3;
        const ushort4 xS = *(const ushort4*)(xt + (size_t)wid * 256 + lane * 4);
        v0 = fmaf(q0, hbits(xS.x), v0); v1 = fmaf(q1, hbits(xS.y), v1);
        v2 = fmaf(q2, hbits(xS.z), v2); v3 = fmaf(q3, hbits(xS.w), v3);
    }
    float o = (v0 / sp0 + v1 / sp1 + v2 / sp2 + v3 / sp3) * 0.25f + cvt<T>(bias[lane]);
    o = o > 0.f ? o : 0.f;                      // relu
    o *= cvt<T>(fc_w[lane]);                    // fc_w is [64,1]
#pragma unroll
    for (int off = 32; off > 0; off >>= 1) o += __shfl_down(o, off, 64);
    if (lane == 0) out[wid] = o + cvt<T>(fc_b[0]);   // fp32 output
}

__global__ __launch_bounds__(256) void k_aggregate(const int* __restrict__ cnt,
                                                   const int* __restrict__ col_pad,
                                                   const float* __restrict__ a_src,
                                                   const float* __restrict__ a_dst,
                                                   const unsigned short* __restrict__ xt,
                                                   const void* __restrict__ bias,
                                                   const void* __restrict__ fc_w,
                                                   const void* __restrict__ fc_b,
                                                   const int* __restrict__ flags,
                                                   float* __restrict__ out) {
    __shared__ int    cS[4 * 64];               // hoisted: single allocation
    __shared__ float4 peS[4 * 64];
    if (flags[1])
        agg_body<float>(cnt, col_pad, a_src, a_dst, xt, (const float*)bias,
                        (const float*)fc_w, (const float*)fc_b, out, cS, peS);
    else
        agg_body<__hip_bfloat16>(cnt, col_pad, a_src, a_dst, xt,
                                 (const __hip_bfloat16*)bias,
                                 (const __hip_bfloat16*)fc_w,
                                 (const __hip_bfloat16*)fc_b, out, cS, peS);
}

extern "C" void kernel_launch(void* const* d_in, const int* in_sizes, int n_in,
                              void* d_out, int out_size, void* d_ws, size_t ws_size,
                              hipStream_t stream) {
    const void* x       = d_in[0];
    const int*  ei      = (const int*)d_in[1];
    const void* W       = d_in[2];
    const void* att_src = d_in[3];
    const void* att_dst = d_in[4];
    const void* bias    = d_in[5];
    const void* fc_w    = d_in[6];
    const void* fc_b    = d_in[7];
    float* out = (float*)d_out;

    char* wsb = (char*)d_ws;
    unsigned short* xt = (unsigned short*)wsb;                   // 25.6 MB (f16)
    unsigned short* Bpack = (unsigned short*)(wsb + (size_t)N_NODES * 512); // 34 KB
    float*  a_src  = (float*)(Bpack + NTILE * 1024);             // 800 KB (16B aligned)
    float*  a_dst  = a_src + N_NODES * HEADS;                    // 800 KB (16B aligned)
    int*    col_pad= (int*)(a_dst + N_NODES * HEADS);            // 12.8 MB
    int*    cnt    = col_pad + (size_t)N_NODES * CAP;            // 200 KB
    int*    flags  = cnt + N_NODES;

    k_init<<<NB + 1, 256, 0, stream>>>((const unsigned*)x, ei, W, att_src, att_dst,
                                       cnt, flags, Bpack);
    k_scatter<<<(N_EDGES + 255) / 256, 256, 0, stream>>>(ei, flags, cnt, col_pad);
    k_transform<<<(N_NODES + 63) / 64, 256, 0, stream>>>(x, Bpack, flags, xt,
                                                         a_src, a_dst);
    k_aggregate<<<((size_t)N_NODES * 64 + 255) / 256, 256, 0, stream>>>(
        cnt, col_pad, a_src, a_dst, xt, bias, fc_w, fc_b, flags, out);
}

// Round 14
// 206.226 us; speedup vs baseline: 1.0439x; 1.0409x over previous
//
#include <hip/hip_runtime.h>
#include <hip/hip_bf16.h>

#define N_NODES 50000
#define N_EDGES 800000
#define HEADS   4
#define NEG_SLOPE 0.2f
#define SB      256
#define NB      ((N_NODES + SB - 1) / SB)   // 196 blocks for cnt-zeroing
#define NTILE   17                    // 16 xt tiles + 1 attention tile
#define CAP     64                    // bucket capacity; P(deg>64)~1e-18/node
#define NT      ((N_NODES + 63) / 64)       // 782 mid blocks
#define EPB     1024                  // edges scattered per mid block (782*1024>=800K)

typedef __attribute__((ext_vector_type(8))) _Float16 half8;  // 8 f16 (4 VGPRs)
typedef __attribute__((ext_vector_type(4))) float f32x4;     // MFMA acc

template <typename T> __device__ __forceinline__ float cvt(T v);
template <> __device__ __forceinline__ float cvt<float>(float v) { return v; }
template <> __device__ __forceinline__ float cvt<__hip_bfloat16>(__hip_bfloat16 v) {
    return __bfloat162float(v);
}
__device__ __forceinline__ unsigned short f2h(float f) {     // f32 -> f16 bits (RNE)
    _Float16 h = (_Float16)f;
    return __builtin_bit_cast(unsigned short, h);
}
__device__ __forceinline__ float hbits(unsigned short u) {   // f16 bits -> f32
    return (float)__builtin_bit_cast(_Float16, u);           // folds into v_fma_mix
}
__device__ __forceinline__ int probe_fp32(const unsigned* xw) {
    int sane = 0;
    for (int j = 0; j < 64; ++j) {
        unsigned e = (xw[j] >> 7) & 0xFF;    // exponent of low half viewed as bf16
        sane += (e >= 90 && e <= 141);
    }
    return sane < 32;                        // junk low halves => fp32 buffer
}

// ---------------- prep: fold att vectors + pack 17 B-fragment tiles (f16) ----
// Tiles 0..15: column-permuted W so xt layout is [node][ch*4+h]; tile 16:
// cols 0..3 = WaS (a_src), 4..7 = WaD (a_dst), 8..15 = 0. B layout (HW-
// verified R9-R13): value(l, q, j) = B[k = q*32 + (l>>4)*8 + j][n = l&15].
template <typename T>
__device__ __forceinline__ void prep_body(const T* __restrict__ W,
                                          const T* __restrict__ att_src,
                                          const T* __restrict__ att_dst,
                                          unsigned short* __restrict__ Bpack,
                                          float* __restrict__ waS,
                                          float* __restrict__ waD) {
    int t = threadIdx.x;                     // t = k*4 + h
    int k = t >> 2, h = t & 3;
    float s = 0.f, d = 0.f;
    for (int c = 0; c < 64; ++c) {
        float w = cvt<T>(W[k * 256 + h * 64 + c]);
        s = fmaf(w, cvt<T>(att_src[h * 64 + c]), s);
        d = fmaf(w, cvt<T>(att_dst[h * 64 + c]), d);
    }
    waS[t] = s;
    waD[t] = d;
    __syncthreads();
    for (int idx = threadIdx.x; idx < NTILE * 128; idx += 256) {
        int tt = idx >> 7, q = (idx >> 6) & 1, l = idx & 63;
        int n = l & 15;
        int kbase = q * 32 + ((l >> 4) & 3) * 8;
        if (tt < 16) {
            int oc = ((tt * 16 + n) & 3) * 64 + ((tt * 16 + n) >> 2);
#pragma unroll
            for (int j = 0; j < 8; ++j)
                Bpack[idx * 8 + j] = f2h(cvt<T>(W[(kbase + j) * 256 + oc]));
        } else {
#pragma unroll
            for (int j = 0; j < 8; ++j) {
                int kk = kbase + j;
                float v = (n < 4) ? waS[kk * 4 + n]
                        : (n < 8) ? waD[kk * 4 + (n - 4)] : 0.f;
                Bpack[idx * 8 + j] = f2h(v);
            }
        }
    }
}

// ------------- fused: zero cnt + dtype probes (block 0) + prep (block NB) ----
// flags[0]: edge_index is int64. flags[1]: float inputs are fp32.
__global__ __launch_bounds__(256) void k_init(const unsigned* __restrict__ xw,
                                              const int* __restrict__ ei,
                                              const void* __restrict__ W,
                                              const void* __restrict__ att_src,
                                              const void* __restrict__ att_dst,
                                              int* __restrict__ cnt,
                                              int* __restrict__ flags,
                                              unsigned short* __restrict__ Bpack) {
    __shared__ float waS[256], waD[256];     // single allocation (kernel scope)
    if (blockIdx.x < NB) {
        int i = blockIdx.x * blockDim.x + threadIdx.x;
        if (i < N_NODES) cnt[i] = 0;
        if (blockIdx.x == 0 && threadIdx.x == 0) {
            int all0 = 1;
            for (int j = 1; j < 64; j += 2) all0 &= (ei[j] == 0);
            flags[0] = all0;
            flags[1] = probe_fp32(xw);
        }
    } else {
        __shared__ int f32sh;
        if (threadIdx.x == 0) f32sh = probe_fp32(xw);   // local probe (race-free)
        __syncthreads();
        if (f32sh)
            prep_body<float>((const float*)W, (const float*)att_src,
                             (const float*)att_dst, Bpack, waS, waD);
        else
            prep_body<__hip_bfloat16>((const __hip_bfloat16*)W,
                                      (const __hip_bfloat16*)att_src,
                                      (const __hip_bfloat16*)att_dst, Bpack,
                                      waS, waD);
    }
}

// ---------------- MFMA transform body: xt = x @ Wp + attention logits --------
// Block = 64 rows, 4 waves; wave w: rows 16w..16w+15, 17 n-tiles, K=64.
// C layout (HW-verified): col=lane&15, row=quad*4+reg. Tile 16 cols 0..7 are
// a_src/a_dst heads -> direct fp32 global writes. xt stored as f16.
template <typename T>
__device__ __forceinline__ void gemm_body(const T* __restrict__ x,
                                          const unsigned short* __restrict__ Bpack,
                                          unsigned short* __restrict__ xt,
                                          float* __restrict__ a_src,
                                          float* __restrict__ a_dst,
                                          unsigned short* __restrict__ tile) {
    const int tid = threadIdx.x;
    const int wav = tid >> 6, lane = tid & 63;
    const int quad = lane >> 4, r15 = lane & 15;
    const int m0 = blockIdx.x * 64;
    int gr = m0 + wav * 16 + r15;               // this lane's A row (m = lane&15)
    if (gr >= N_NODES) gr = N_NODES - 1;        // clamp; stores guarded
    half8 afrag[2];
#pragma unroll
    for (int q = 0; q < 2; ++q) {
        const T* xp = x + (size_t)gr * 64 + q * 32 + quad * 8;
#pragma unroll
        for (int j = 0; j < 8; ++j)
            afrag[q][j] = (_Float16)cvt<T>(xp[j]);
    }
    f32x4 acc[NTILE];
#pragma unroll
    for (int t = 0; t < NTILE; ++t) acc[t] = (f32x4){0.f, 0.f, 0.f, 0.f};
    const half8* bp = (const half8*)Bpack;
#pragma unroll
    for (int t = 0; t < NTILE; ++t) {
        half8 b0 = bp[(t * 2 + 0) * 64 + lane];   // L1-resident (34 KB total)
        half8 b1 = bp[(t * 2 + 1) * 64 + lane];
        acc[t] = __builtin_amdgcn_mfma_f32_16x16x32_f16(afrag[0], b0, acc[t], 0, 0, 0);
        acc[t] = __builtin_amdgcn_mfma_f32_16x16x32_f16(afrag[1], b1, acc[t], 0, 0, 0);
    }
#pragma unroll
    for (int t = 0; t < 16; ++t)
#pragma unroll
        for (int r = 0; r < 4; ++r)
            tile[(wav * 16 + quad * 4 + r) * 264 + t * 16 + r15] = f2h(acc[t][r]);
    if (r15 < 8) {                               // tile 16: attention logits, fp32
#pragma unroll
        for (int r = 0; r < 4; ++r) {
            int grow = m0 + wav * 16 + quad * 4 + r;
            if (grow < N_NODES) {
                if (r15 < 4) a_src[grow * HEADS + r15]       = acc[16][r];
                else         a_dst[grow * HEADS + (r15 - 4)] = acc[16][r];
            }
        }
    }
    __syncthreads();
    for (int idx = tid; idx < 64 * 32; idx += 256) {   // 64 rows x 32 chunks x 16B
        int row = idx >> 5, cc = idx & 31;
        int grow = m0 + row;
        if (grow < N_NODES) {
            uint4 v = *(const uint4*)&tile[row * 264 + cc * 8];
            *(uint4*)(xt + (size_t)grow * 256 + cc * 8) = v;
        }
    }
}

// ---------------- fused mid: every block scatters EPB edges AND transforms ---
// Scatter phase first (4 batched edges/thread: independent atomic chains),
// its latency hides under co-resident waves' MFMA/LDS work. Unlike R12, no
// dedicated scatter blocks exist to be strangled by the LDS reservation.
__global__ __launch_bounds__(256) void k_mid(const void* __restrict__ x,
                                             const unsigned short* __restrict__ Bpack,
                                             const int* __restrict__ ei,
                                             const int* __restrict__ flags,
                                             int* __restrict__ cnt,
                                             int* __restrict__ col_pad,
                                             unsigned short* __restrict__ xt,
                                             float* __restrict__ a_src,
                                             float* __restrict__ a_dst) {
    __shared__ unsigned short tile[64 * 264];   // ONE 33.8 KB allocation
    {   // ---- scatter my edge chunk ----
        const int f64 = flags[0];
        const int base = blockIdx.x * EPB + threadIdx.x;
        int srcv[4], dstv[4];
#pragma unroll
        for (int k = 0; k < 4; ++k) {
            int t = base + k * 256;
            if (t < N_EDGES) {
                if (f64) { srcv[k] = ei[2 * t]; dstv[k] = ei[2 * N_EDGES + 2 * t]; }
                else     { srcv[k] = ei[t];     dstv[k] = ei[N_EDGES + t]; }
            } else dstv[k] = -1;
        }
        int pos[4];
#pragma unroll
        for (int k = 0; k < 4; ++k)
            if (dstv[k] >= 0) pos[k] = atomicAdd(cnt + dstv[k], 1);
#pragma unroll
        for (int k = 0; k < 4; ++k)
            if (dstv[k] >= 0 && pos[k] < CAP)
                col_pad[dstv[k] * CAP + pos[k]] = srcv[k];
    }
    // ---- transform my 64 rows ----
    if (flags[1]) gemm_body<float>((const float*)x, Bpack, xt, a_src, a_dst, tile);
    else          gemm_body<__hip_bfloat16>((const __hip_bfloat16*)x, Bpack, xt,
                                            a_src, a_dst, tile);
}

// ---------------- fused aggregate: softmax + weighted sum + mean/bias/relu/fc
// One wave per dst node; lane = channel. Denominators accumulated from the
// BROADCAST LDS pe reads inside the j-loop (all lanes build the identical
// full-row sum) -- no butterfly reduction. Self-loop analytic. x8 unroll
// keeps 8 independent 512 B xt gathers in flight; f16 via v_fma_mix.
template <typename T>
__device__ __forceinline__ void agg_body(const int* __restrict__ cnt,
                                         const int* __restrict__ col_pad,
                                         const float* __restrict__ a_src,
                                         const float* __restrict__ a_dst,
                                         const unsigned short* __restrict__ xt,
                                         const T* __restrict__ bias,
                                         const T* __restrict__ fc_w,
                                         const T* __restrict__ fc_b,
                                         float* __restrict__ out,
                                         int* __restrict__ cS,
                                         float4* __restrict__ peS) {
    const int tid = threadIdx.x;
    const int wav = tid >> 6, lane = tid & 63;
    const int wid = (blockIdx.x * blockDim.x + tid) >> 6;   // dst node
    if (wid >= N_NODES) return;
    int* cSw = cS + wav * 64;
    float4* peSw = peS + wav * 64;
    int n = cnt[wid]; n = n > CAP ? CAP : n;
    const float4 ad = ((const float4*)a_dst)[wid];          // uniform
    const float4 as_self = ((const float4*)a_src)[wid];
    float v0 = 0.f, v1 = 0.f, v2 = 0.f, v3 = 0.f;
    float sp0 = 0.f, sp1 = 0.f, sp2 = 0.f, sp3 = 0.f;       // identical in all lanes
    for (int base = 0; base < n; base += 64) {
        int m = n - base; m = m > 64 ? 64 : m;
        if (lane < m) {
            int mycol = col_pad[wid * CAP + base + lane];   // coalesced
            const float4 as = ((const float4*)a_src)[mycol];
            float e0 = as.x + ad.x, e1 = as.y + ad.y;
            float e2 = as.z + ad.z, e3 = as.w + ad.w;
            e0 = e0 > 0.f ? e0 : NEG_SLOPE * e0;  e1 = e1 > 0.f ? e1 : NEG_SLOPE * e1;
            e2 = e2 > 0.f ? e2 : NEG_SLOPE * e2;  e3 = e3 > 0.f ? e3 : NEG_SLOPE * e3;
            float4 pe = make_float4(__expf(e0), __expf(e1), __expf(e2), __expf(e3));
            cSw[lane] = mycol;
            peSw[lane] = pe;
        }
        int j = 0;
        for (; j + 8 <= m; j += 8) {
            int s0 = cSw[j],     s1 = cSw[j + 1];
            int s2 = cSw[j + 2], s3 = cSw[j + 3];
            int s4 = cSw[j + 4], s5 = cSw[j + 5];
            int s6 = cSw[j + 6], s7 = cSw[j + 7];
            const ushort4 xA = *(const ushort4*)(xt + (size_t)s0 * 256 + lane * 4);
            const ushort4 xB = *(const ushort4*)(xt + (size_t)s1 * 256 + lane * 4);
            const ushort4 xC = *(const ushort4*)(xt + (size_t)s2 * 256 + lane * 4);
            const ushort4 xD = *(const ushort4*)(xt + (size_t)s3 * 256 + lane * 4);
            const ushort4 xE = *(const ushort4*)(xt + (size_t)s4 * 256 + lane * 4);
            const ushort4 xF = *(const ushort4*)(xt + (size_t)s5 * 256 + lane * 4);
            const ushort4 xG = *(const ushort4*)(xt + (size_t)s6 * 256 + lane * 4);
            const ushort4 xH = *(const ushort4*)(xt + (size_t)s7 * 256 + lane * 4);
            float4 p0 = peSw[j],     p1 = peSw[j + 1];
            float4 p2 = peSw[j + 2], p3 = peSw[j + 3];
            float4 p4 = peSw[j + 4], p5 = peSw[j + 5];
            float4 p6 = peSw[j + 6], p7 = peSw[j + 7];
            sp0 += ((p0.x + p1.x) + (p2.x + p3.x)) + ((p4.x + p5.x) + (p6.x + p7.x));
            sp1 += ((p0.y + p1.y) + (p2.y + p3.y)) + ((p4.y + p5.y) + (p6.y + p7.y));
            sp2 += ((p0.z + p1.z) + (p2.z + p3.z)) + ((p4.z + p5.z) + (p6.z + p7.z));
            sp3 += ((p0.w + p1.w) + (p2.w + p3.w)) + ((p4.w + p5.w) + (p6.w + p7.w));
            v0 = fmaf(p0.x, hbits(xA.x), v0); v1 = fmaf(p0.y, hbits(xA.y), v1);
            v2 = fmaf(p0.z, hbits(xA.z), v2); v3 = fmaf(p0.w, hbits(xA.w), v3);
            v0 = fmaf(p1.x, hbits(xB.x), v0); v1 = fmaf(p1.y, hbits(xB.y), v1);
            v2 = fmaf(p1.z, hbits(xB.z), v2); v3 = fmaf(p1.w, hbits(xB.w), v3);
            v0 = fmaf(p2.x, hbits(xC.x), v0); v1 = fmaf(p2.y, hbits(xC.y), v1);
            v2 = fmaf(p2.z, hbits(xC.z), v2); v3 = fmaf(p2.w, hbits(xC.w), v3);
            v0 = fmaf(p3.x, hbits(xD.x), v0); v1 = fmaf(p3.y, hbits(xD.y), v1);
            v2 = fmaf(p3.z, hbits(xD.z), v2); v3 = fmaf(p3.w, hbits(xD.w), v3);
            v0 = fmaf(p4.x, hbits(xE.x), v0); v1 = fmaf(p4.y, hbits(xE.y), v1);
            v2 = fmaf(p4.z, hbits(xE.z), v2); v3 = fmaf(p4.w, hbits(xE.w), v3);
            v0 = fmaf(p5.x, hbits(xF.x), v0); v1 = fmaf(p5.y, hbits(xF.y), v1);
            v2 = fmaf(p5.z, hbits(xF.z), v2); v3 = fmaf(p5.w, hbits(xF.w), v3);
            v0 = fmaf(p6.x, hbits(xG.x), v0); v1 = fmaf(p6.y, hbits(xG.y), v1);
            v2 = fmaf(p6.z, hbits(xG.z), v2); v3 = fmaf(p6.w, hbits(xG.w), v3);
            v0 = fmaf(p7.x, hbits(xH.x), v0); v1 = fmaf(p7.y, hbits(xH.y), v1);
            v2 = fmaf(p7.z, hbits(xH.z), v2); v3 = fmaf(p7.w, hbits(xH.w), v3);
        }
        for (; j < m; ++j) {
            int s0 = cSw[j];
            const ushort4 xA = *(const ushort4*)(xt + (size_t)s0 * 256 + lane * 4);
            float4 p0 = peSw[j];
            sp0 += p0.x; sp1 += p0.y; sp2 += p0.z; sp3 += p0.w;
            v0 = fmaf(p0.x, hbits(xA.x), v0); v1 = fmaf(p0.y, hbits(xA.y), v1);
            v2 = fmaf(p0.z, hbits(xA.z), v2); v3 = fmaf(p0.w, hbits(xA.w), v3);
        }
    }
    {   // self loop: e = a_src[wid] + a_dst[wid], uniform across lanes
        float e0 = as_self.x + ad.x, e1 = as_self.y + ad.y;
        float e2 = as_self.z + ad.z, e3 = as_self.w + ad.w;
        e0 = e0 > 0.f ? e0 : NEG_SLOPE * e0;  e1 = e1 > 0.f ? e1 : NEG_SLOPE * e1;
        e2 = e2 > 0.f ? e2 : NEG_SLOPE * e2;  e3 = e3 > 0.f ? e3 : NEG_SLOPE * e3;
        float q0 = __expf(e0), q1 = __expf(e1), q2 = __expf(e2), q3 = __expf(e3);
        sp0 += q0; sp1 += q1; sp2 += q2; sp3 += q3;
        const ushort4 xS = *(const ushort4*)(xt + (size_t)wid * 256 + lane * 4);
        v0 = fmaf(q0, hbits(xS.x), v0); v1 = fmaf(q1, hbits(xS.y), v1);
        v2 = fmaf(q2, hbits(xS.z), v2); v3 = fmaf(q3, hbits(xS.w), v3);
    }
    float o = (v0 / sp0 + v1 / sp1 + v2 / sp2 + v3 / sp3) * 0.25f + cvt<T>(bias[lane]);
    o = o > 0.f ? o : 0.f;                      // relu
    o *= cvt<T>(fc_w[lane]);                    // fc_w is [64,1]
#pragma unroll
    for (int off = 32; off > 0; off >>= 1) o += __shfl_down(o, off, 64);
    if (lane == 0) out[wid] = o + cvt<T>(fc_b[0]);   // fp32 output
}

__global__ __launch_bounds__(256) void k_aggregate(const int* __restrict__ cnt,
                                                   const int* __restrict__ col_pad,
                                                   const float* __restrict__ a_src,
                                                   const float* __restrict__ a_dst,
                                                   const unsigned short* __restrict__ xt,
                                                   const void* __restrict__ bias,
                                                   const void* __restrict__ fc_w,
                                                   const void* __restrict__ fc_b,
                                                   const int* __restrict__ flags,
                                                   float* __restrict__ out) {
    __shared__ int    cS[4 * 64];               // single allocation (kernel scope)
    __shared__ float4 peS[4 * 64];
    if (flags[1])
        agg_body<float>(cnt, col_pad, a_src, a_dst, xt, (const float*)bias,
                        (const float*)fc_w, (const float*)fc_b, out, cS, peS);
    else
        agg_body<__hip_bfloat16>(cnt, col_pad, a_src, a_dst, xt,
                                 (const __hip_bfloat16*)bias,
                                 (const __hip_bfloat16*)fc_w,
                                 (const __hip_bfloat16*)fc_b, out, cS, peS);
}

extern "C" void kernel_launch(void* const* d_in, const int* in_sizes, int n_in,
                              void* d_out, int out_size, void* d_ws, size_t ws_size,
                              hipStream_t stream) {
    const void* x       = d_in[0];
    const int*  ei      = (const int*)d_in[1];
    const void* W       = d_in[2];
    const void* att_src = d_in[3];
    const void* att_dst = d_in[4];
    const void* bias    = d_in[5];
    const void* fc_w    = d_in[6];
    const void* fc_b    = d_in[7];
    float* out = (float*)d_out;

    char* wsb = (char*)d_ws;
    unsigned short* xt = (unsigned short*)wsb;                   // 25.6 MB (f16)
    unsigned short* Bpack = (unsigned short*)(wsb + (size_t)N_NODES * 512); // 34 KB
    float*  a_src  = (float*)(Bpack + NTILE * 1024);             // 800 KB (16B aligned)
    float*  a_dst  = a_src + N_NODES * HEADS;                    // 800 KB (16B aligned)
    int*    col_pad= (int*)(a_dst + N_NODES * HEADS);            // 12.8 MB
    int*    cnt    = col_pad + (size_t)N_NODES * CAP;            // 200 KB
    int*    flags  = cnt + N_NODES;

    k_init<<<NB + 1, 256, 0, stream>>>((const unsigned*)x, ei, W, att_src, att_dst,
                                       cnt, flags, Bpack);
    k_mid<<<NT, 256, 0, stream>>>(x, Bpack, ei, flags, cnt, col_pad,
                                  xt, a_src, a_dst);
    k_aggregate<<<((size_t)N_NODES * 64 + 255) / 256, 256, 0, stream>>>(
        cnt, col_pad, a_src, a_dst, xt, bias, fc_w, fc_b, flags, out);
}